// Round 6
// baseline (105.283 us; speedup 1.0000x reference)
//
#include <hip/hip_runtime.h>

#define BATCH 8
#define NTOK 16384

typedef __attribute__((ext_vector_type(8))) short bf16x8;
typedef __attribute__((ext_vector_type(4))) float f32x4;

#define MFMA(a, b, c) __builtin_amdgcn_mfma_f32_16x16x32_bf16(a, b, c, 0, 0, 0)

// proven R2 path: RNE f32->bf16 via bit ops (no inline asm anywhere)
__device__ __forceinline__ short f2bf(float f) {
  unsigned u = __builtin_bit_cast(unsigned, f);
  u = (u + 0x7fffu + ((u >> 16) & 1u)) >> 16;  // RNE
  return (short)u;
}

__device__ __forceinline__ bf16x8 cvt8(f32x4 v0, f32x4 v1) {
  bf16x8 a;
  a[0] = f2bf(v0[0]); a[1] = f2bf(v0[1]); a[2] = f2bf(v0[2]); a[3] = f2bf(v0[3]);
  a[4] = f2bf(v1[0]); a[5] = f2bf(v1[1]); a[6] = f2bf(v1[2]); a[7] = f2bf(v1[3]);
  return a;
}

// ---------------- prep: weight transpose/convert to bf16 (R2-exact) -------
__global__ void prep_k(const float* __restrict__ w_sr, const float* __restrict__ w_q,
                       const float* __restrict__ w_proj, short* __restrict__ W2T,
                       short* __restrict__ Wq, short* __restrict__ Wp) {
  int i = blockIdx.x * 256 + threadIdx.x;
  if (i < 64 * 4096) {
    int o = i >> 12, k = i & 4095, t = k >> 6, c = k & 63;
    W2T[i] = f2bf(w_sr[(o << 12) + (c << 6) + t]);
  } else if (i < 64 * 4096 + 4096) {
    int j = i - 64 * 4096;
    Wq[j] = f2bf(w_q[j] * 0.125f);
  } else if (i < 64 * 4096 + 8192) {
    int j = i - 64 * 4096 - 4096;
    Wp[j] = f2bf(w_proj[j]);
  }
}

// ---------------- conv (8x8 stride-8 patches) as MFMA GEMM (R2-exact) -----
__global__ __launch_bounds__(256) void conv_k(const float* __restrict__ x,
                                              const short* __restrict__ W2T,
                                              float* __restrict__ convP) {
  const int tid = threadIdx.x;
  const int lane = tid & 63;
  const int nt = tid >> 6;
  const int g = lane >> 4;
  const int kq = lane & 15;
  const int pblk = blockIdx.x >> 2;
  const int split = blockIdx.x & 3;
  const int pbase = pblk << 4;
  const int b = pbase >> 8;
  const int p = pbase + kq;
  const int pb = p & 255;
  const int rowbase = ((pb >> 4) << 10) + ((pb & 15) << 3);
  const size_t xb = (size_t)b * NTOK * 64;

  f32x4 acc = (f32x4){0.f, 0.f, 0.f, 0.f};
  const int c0 = split << 5;
#pragma unroll 4
  for (int c32 = c0; c32 < c0 + 32; ++c32) {
    int t = c32 >> 1;
    int hc = (c32 & 1) << 5;
    int token = rowbase + ((t >> 3) << 7) + (t & 7);
    const float* xp = x + xb + ((size_t)token << 6) + hc + (g << 3);
    bf16x8 a = cvt8(*(const f32x4*)xp, *(const f32x4*)(xp + 4));
    bf16x8 wb = *(const bf16x8*)(W2T + ((nt * 16 + kq) << 12) + (c32 << 5) + (g << 3));
    acc = MFMA(a, wb, acc);
  }
#pragma unroll
  for (int r = 0; r < 4; ++r) {
    int prow = pbase + g * 4 + r;
    convP[((split << 11) + prow) * 64 + nt * 16 + kq] = acc[r];
  }
}

// ---------------- bias + LayerNorm + kv projection (R2-exact) -------------
__global__ __launch_bounds__(256) void kv_k(const float* __restrict__ convP,
                                            const float* __restrict__ b_sr,
                                            const float* __restrict__ ln_g,
                                            const float* __restrict__ ln_b,
                                            const float* __restrict__ w_kv,
                                            short* __restrict__ Kw,
                                            short* __restrict__ Vtw) {
  __shared__ float wT[64 * 128];  // [c][d2] swizzled: +(d2 ^ (c&31))
  __shared__ float raw[2][64];
  __shared__ float rowz[2][64];
  const int tid = threadIdx.x;
#pragma unroll 8
  for (int i = 0; i < 32; ++i) {
    int idx = i * 256 + tid;
    int d2 = idx >> 6, c = idx & 63;
    wT[(c << 7) + (d2 ^ (c & 31))] = w_kv[idx];
  }
  const int gr0 = blockIdx.x << 1;
  if (tid < 128) {
    int r = tid >> 6, c = tid & 63;
    int gr = gr0 + r;
    float y = b_sr[c];
#pragma unroll
    for (int s = 0; s < 4; ++s) y += convP[((s << 11) + gr) * 64 + c];
    raw[r][c] = y;
  }
  __syncthreads();
  if (tid < 128) {
    int r = tid >> 6, c = tid & 63;
    float y = raw[r][c];
    float s1 = y, s2 = y * y;
#pragma unroll
    for (int off = 1; off < 64; off <<= 1) {
      s1 += __shfl_xor(s1, off);
      s2 += __shfl_xor(s2, off);
    }
    float mu = s1 * 0.015625f;
    float var = s2 * 0.015625f - mu * mu;
    float rs = rsqrtf(var + 1e-5f);
    rowz[r][c] = (y - mu) * rs * ln_g[c] + ln_b[c];
  }
  __syncthreads();
  {
    int r = tid >> 7, d = tid & 127;
    float acc = 0.f;
#pragma unroll
    for (int c = 0; c < 64; ++c) acc += rowz[r][c] * wT[(c << 7) + (d ^ (c & 31))];
    int gr = gr0 + r;
    int bb = gr >> 8, m = gr & 255;
    if (d < 64)
      Kw[((bb << 8) + m) * 64 + d] = f2bf(acc);
    else
      Vtw[((bb << 6) + (d - 64)) * 256 + m] = f2bf(acc);
  }
}

// ---------------- fused q-proj + attention + out-proj (NEW, no asm) -------
// 4 waves/block, 32 queries/wave, no cross-wave state (no syncthreads).
// K/V read directly from global (L1/L2-resident: 64KB/batch).
// Scr = 4KB/wave for the C-layout -> A-fragment transposes.
__global__ __launch_bounds__(256, 4) void attn_k(
    const float* __restrict__ x, const short* __restrict__ Kw,
    const short* __restrict__ Vtw, const short* __restrict__ Wq,
    const short* __restrict__ Wp, const float* __restrict__ bproj,
    float* __restrict__ out) {
  __shared__ short Scr[4 * 2048];  // 4KB per wave

  const int tid = threadIdx.x;
  const int lane = tid & 63;
  const int wid = tid >> 6;
  const int b = blockIdx.x >> 7;
  const int n0 = (blockIdx.x & 127) << 7;

  const int g = lane >> 4;
  const int kq = lane & 15;
  short* scr = &Scr[wid << 11];
  const int tok0 = n0 + wid * 32;
  const size_t xbase = ((size_t)b * NTOK + tok0) * 64;
  const short* Kb = Kw + ((size_t)b << 14);   // [256][64]
  const short* Vb = Vtw + ((size_t)b << 14);  // [64][256]

  // ---- q projection ----
  f32x4 qa[2][4];
#pragma unroll
  for (int m = 0; m < 2; ++m)
#pragma unroll
    for (int nt = 0; nt < 4; ++nt) qa[m][nt] = (f32x4){0.f, 0.f, 0.f, 0.f};
  bf16x8 xa[2][2];
#pragma unroll
  for (int m = 0; m < 2; ++m)
#pragma unroll
    for (int kc = 0; kc < 2; ++kc) {
      const float* p = x + xbase + (size_t)(m * 16 + kq) * 64 + kc * 32 + g * 8;
      xa[m][kc] = cvt8(*(const f32x4*)p, *(const f32x4*)(p + 4));
    }
#pragma unroll
  for (int kc = 0; kc < 2; ++kc)
#pragma unroll
    for (int nt = 0; nt < 4; ++nt) {
      bf16x8 wb = *(const bf16x8*)(Wq + (nt * 16 + kq) * 64 + kc * 32 + g * 8);
#pragma unroll
      for (int m = 0; m < 2; ++m) qa[m][nt] = MFMA(xa[m][kc], wb, qa[m][nt]);
    }
  // stage q [32][64] bf16 (swizzled), read back as A-fragments
#pragma unroll
  for (int m = 0; m < 2; ++m)
#pragma unroll
    for (int nt = 0; nt < 4; ++nt)
#pragma unroll
      for (int r = 0; r < 4; ++r) {
        int row = m * 16 + g * 4 + r;
        int cb = ((nt * 16 + kq) << 1) ^ ((row & 7) << 4);
        scr[(row << 6) + (cb >> 1)] = f2bf(qa[m][nt][r]);
      }
  bf16x8 qf[2][2];
#pragma unroll
  for (int m = 0; m < 2; ++m)
#pragma unroll
    for (int kc = 0; kc < 2; ++kc) {
      int row = m * 16 + kq;
      int cb = (kc * 64 + g * 16) ^ ((row & 7) << 4);
      qf[m][kc] = *(const bf16x8*)(scr + (row << 6) + (cb >> 1));
    }

  float rsum[2][4];
#pragma unroll
  for (int m = 0; m < 2; ++m)
#pragma unroll
    for (int r = 0; r < 4; ++r) rsum[m][r] = 0.f;
  f32x4 pv[2][4];
#pragma unroll
  for (int m = 0; m < 2; ++m)
#pragma unroll
    for (int nd = 0; nd < 4; ++nd) pv[m][nd] = (f32x4){0.f, 0.f, 0.f, 0.f};

#pragma unroll
  for (int qr = 0; qr < 4; ++qr) {  // 64-key quarters
    f32x4 sa[2][4];
#pragma unroll
    for (int m = 0; m < 2; ++m)
#pragma unroll
      for (int ntk = 0; ntk < 4; ++ntk) sa[m][ntk] = (f32x4){0.f, 0.f, 0.f, 0.f};
    // S = q @ K^T   (K fragments straight from global; L1/L2-hot)
#pragma unroll
    for (int ntk = 0; ntk < 4; ++ntk) {
      int key = qr * 64 + ntk * 16 + kq;
#pragma unroll
      for (int kc = 0; kc < 2; ++kc) {
        bf16x8 kb = *(const bf16x8*)(Kb + (key << 6) + kc * 32 + g * 8);
#pragma unroll
        for (int m = 0; m < 2; ++m) sa[m][ntk] = MFMA(qf[m][kc], kb, sa[m][ntk]);
      }
    }
    // exp + rowsum + stage E [32][64] bf16 (swizzled)
#pragma unroll
    for (int m = 0; m < 2; ++m)
#pragma unroll
      for (int ntk = 0; ntk < 4; ++ntk)
#pragma unroll
        for (int r = 0; r < 4; ++r) {
          float e = __expf(sa[m][ntk][r]);
          rsum[m][r] += e;
          int row = m * 16 + g * 4 + r;
          int cb = ((ntk * 16 + kq) << 1) ^ ((row & 7) << 4);
          scr[(row << 6) + (cb >> 1)] = f2bf(e);
        }
    // PV for this quarter (V^T fragments straight from global)
#pragma unroll
    for (int kc2 = 0; kc2 < 2; ++kc2) {
      bf16x8 pa[2];
#pragma unroll
      for (int m = 0; m < 2; ++m) {
        int row = m * 16 + kq;
        int cb = (kc2 * 64 + g * 16) ^ ((row & 7) << 4);
        pa[m] = *(const bf16x8*)(scr + (row << 6) + (cb >> 1));
      }
#pragma unroll
      for (int nd = 0; nd < 4; ++nd) {
        int d = nd * 16 + kq;
        bf16x8 vb = *(const bf16x8*)(Vb + (d << 8) + qr * 64 + kc2 * 32 + g * 8);
#pragma unroll
        for (int m = 0; m < 2; ++m) pv[m][nd] = MFMA(pa[m], vb, pv[m][nd]);
      }
    }
  }
  // rowsum reduce across the 16 kq lanes, then normalize
#pragma unroll
  for (int m = 0; m < 2; ++m)
#pragma unroll
    for (int r = 0; r < 4; ++r) {
      float s = rsum[m][r];
      s += __shfl_xor(s, 1);
      s += __shfl_xor(s, 2);
      s += __shfl_xor(s, 4);
      s += __shfl_xor(s, 8);
      rsum[m][r] = 1.0f / s;
    }
#pragma unroll
  for (int m = 0; m < 2; ++m)
#pragma unroll
    for (int nd = 0; nd < 4; ++nd)
#pragma unroll
      for (int r = 0; r < 4; ++r) pv[m][nd][r] *= rsum[m][r];
  // stage out_attn [32][64] bf16, read back as A-fragments
#pragma unroll
  for (int m = 0; m < 2; ++m)
#pragma unroll
    for (int nd = 0; nd < 4; ++nd)
#pragma unroll
      for (int r = 0; r < 4; ++r) {
        int row = m * 16 + g * 4 + r;
        int cb = ((nd * 16 + kq) << 1) ^ ((row & 7) << 4);
        scr[(row << 6) + (cb >> 1)] = f2bf(pv[m][nd][r]);
      }
  bf16x8 of[2][2];
#pragma unroll
  for (int m = 0; m < 2; ++m)
#pragma unroll
    for (int kc = 0; kc < 2; ++kc) {
      int row = m * 16 + kq;
      int cb = (kc * 64 + g * 16) ^ ((row & 7) << 4);
      of[m][kc] = *(const bf16x8*)(scr + (row << 6) + (cb >> 1));
    }
  // out projection
  f32x4 pj[2][4];
#pragma unroll
  for (int m = 0; m < 2; ++m)
#pragma unroll
    for (int nt = 0; nt < 4; ++nt) pj[m][nt] = (f32x4){0.f, 0.f, 0.f, 0.f};
#pragma unroll
  for (int kc = 0; kc < 2; ++kc)
#pragma unroll
    for (int nt = 0; nt < 4; ++nt) {
      bf16x8 wb = *(const bf16x8*)(Wp + (nt * 16 + kq) * 64 + kc * 32 + g * 8);
#pragma unroll
      for (int m = 0; m < 2; ++m) pj[m][nt] = MFMA(of[m][kc], wb, pj[m][nt]);
    }
  // epilogue: two 16-row half-passes through 4KB scratch (f32) + bias + stores
  float* sf = (float*)scr;
  const f32x4* bp4 = (const f32x4*)bproj;
#pragma unroll
  for (int p = 0; p < 2; ++p) {
#pragma unroll
    for (int nt = 0; nt < 4; ++nt)
#pragma unroll
      for (int r = 0; r < 4; ++r) {
        int row = g * 4 + r;  // tile-local
        int j = nt * 16 + kq;
        int cb = (j << 2) ^ ((row & 7) << 4);
        sf[(row << 6) + (cb >> 2)] = pj[p][nt][r];
      }
#pragma unroll
    for (int i = 0; i < 4; ++i) {
      int idx = i * 64 + lane;
      int trow = idx >> 4, seg = idx & 15;
      int cb = (seg << 4) ^ ((trow & 7) << 4);
      f32x4 v = *(const f32x4*)(sf + (trow << 6) + (cb >> 2));
      v += bp4[seg];
      *(f32x4*)(out + xbase + (size_t)(p * 16 + trow) * 64 + seg * 4) = v;
    }
  }
}

extern "C" void kernel_launch(void* const* d_in, const int* in_sizes, int n_in,
                              void* d_out, int out_size, void* d_ws, size_t ws_size,
                              hipStream_t stream) {
  const float* x = (const float*)d_in[0];
  const float* w_q = (const float*)d_in[3];
  const float* w_kv = (const float*)d_in[4];
  const float* w_sr = (const float*)d_in[5];
  const float* b_sr = (const float*)d_in[6];
  const float* ln_g = (const float*)d_in[7];
  const float* ln_b = (const float*)d_in[8];
  const float* w_proj = (const float*)d_in[9];
  const float* b_proj = (const float*)d_in[10];
  float* out = (float*)d_out;

  // workspace layout: identical to the R2-passing run (3,162,112 B total)
  char* ws = (char*)d_ws;
  short* W2T = (short*)(ws);              // 524288 B
  short* Wq = (short*)(ws + 524288);      // 8192 B
  short* Wp = (short*)(ws + 532480);      // 8192 B
  float* convP = (float*)(ws + 540672);   // 4*2048*64*4 = 2097152 B
  short* Kw = (short*)(ws + 2637824);     // 262144 B
  short* Vtw = (short*)(ws + 2899968);    // 262144 B (end 3162112)

  hipLaunchKernelGGL(prep_k, dim3(1056), dim3(256), 0, stream, w_sr, w_q, w_proj,
                     W2T, Wq, Wp);
  hipLaunchKernelGGL(conv_k, dim3(512), dim3(256), 0, stream, x, W2T, convP);
  hipLaunchKernelGGL(kv_k, dim3(1024), dim3(256), 0, stream, convP, b_sr, ln_g,
                     ln_b, w_kv, Kw, Vtw);
  hipLaunchKernelGGL(attn_k, dim3(1024), dim3(256), 0, stream, x, Kw, Vtw, Wq, Wp,
                     b_proj, out);
}

// Round 7
// 77.123 us; speedup vs baseline: 1.3651x; 1.3651x over previous
//
#include <hip/hip_runtime.h>

#define BATCH 8
#define NTOK 16384

typedef __attribute__((ext_vector_type(8))) short bf16x8;
typedef __attribute__((ext_vector_type(4))) float f32x4;

#define MFMA(a, b, c) __builtin_amdgcn_mfma_f32_16x16x32_bf16(a, b, c, 0, 0, 0)

// proven path: RNE f32->bf16 via bit ops (no inline asm anywhere)
__device__ __forceinline__ short f2bf(float f) {
  unsigned u = __builtin_bit_cast(unsigned, f);
  u = (u + 0x7fffu + ((u >> 16) & 1u)) >> 16;  // RNE
  return (short)u;
}

__device__ __forceinline__ bf16x8 cvt8(f32x4 v0, f32x4 v1) {
  bf16x8 a;
  a[0] = f2bf(v0[0]); a[1] = f2bf(v0[1]); a[2] = f2bf(v0[2]); a[3] = f2bf(v0[3]);
  a[4] = f2bf(v1[0]); a[5] = f2bf(v1[1]); a[6] = f2bf(v1[2]); a[7] = f2bf(v1[3]);
  return a;
}

// ---------------- prep: weight transpose/convert to bf16 (R6-exact) -------
__global__ void prep_k(const float* __restrict__ w_sr, const float* __restrict__ w_q,
                       const float* __restrict__ w_proj, short* __restrict__ W2T,
                       short* __restrict__ Wq, short* __restrict__ Wp) {
  int i = blockIdx.x * 256 + threadIdx.x;
  if (i < 64 * 4096) {
    int o = i >> 12, k = i & 4095, t = k >> 6, c = k & 63;
    W2T[i] = f2bf(w_sr[(o << 12) + (c << 6) + t]);
  } else if (i < 64 * 4096 + 4096) {
    int j = i - 64 * 4096;
    Wq[j] = f2bf(w_q[j] * 0.125f);
  } else if (i < 64 * 4096 + 8192) {
    int j = i - 64 * 4096 - 4096;
    Wp[j] = f2bf(w_proj[j]);
  }
}

// ---------------- conv (8x8 stride-8 patches) as MFMA GEMM (R6-exact) -----
__global__ __launch_bounds__(256) void conv_k(const float* __restrict__ x,
                                              const short* __restrict__ W2T,
                                              float* __restrict__ convP) {
  const int tid = threadIdx.x;
  const int lane = tid & 63;
  const int nt = tid >> 6;
  const int g = lane >> 4;
  const int kq = lane & 15;
  const int pblk = blockIdx.x >> 2;
  const int split = blockIdx.x & 3;
  const int pbase = pblk << 4;
  const int b = pbase >> 8;
  const int p = pbase + kq;
  const int pb = p & 255;
  const int rowbase = ((pb >> 4) << 10) + ((pb & 15) << 3);
  const size_t xb = (size_t)b * NTOK * 64;

  f32x4 acc = (f32x4){0.f, 0.f, 0.f, 0.f};
  const int c0 = split << 5;
#pragma unroll 4
  for (int c32 = c0; c32 < c0 + 32; ++c32) {
    int t = c32 >> 1;
    int hc = (c32 & 1) << 5;
    int token = rowbase + ((t >> 3) << 7) + (t & 7);
    const float* xp = x + xb + ((size_t)token << 6) + hc + (g << 3);
    bf16x8 a = cvt8(*(const f32x4*)xp, *(const f32x4*)(xp + 4));
    bf16x8 wb = *(const bf16x8*)(W2T + ((nt * 16 + kq) << 12) + (c32 << 5) + (g << 3));
    acc = MFMA(a, wb, acc);
  }
#pragma unroll
  for (int r = 0; r < 4; ++r) {
    int prow = pbase + g * 4 + r;
    convP[((split << 11) + prow) * 64 + nt * 16 + kq] = acc[r];
  }
}

// ---------------- bias + LayerNorm + kv projection (R6-exact) -------------
__global__ __launch_bounds__(256) void kv_k(const float* __restrict__ convP,
                                            const float* __restrict__ b_sr,
                                            const float* __restrict__ ln_g,
                                            const float* __restrict__ ln_b,
                                            const float* __restrict__ w_kv,
                                            short* __restrict__ Kw,
                                            short* __restrict__ Vtw) {
  __shared__ float wT[64 * 128];  // [c][d2] swizzled: +(d2 ^ (c&31))
  __shared__ float raw[2][64];
  __shared__ float rowz[2][64];
  const int tid = threadIdx.x;
#pragma unroll 8
  for (int i = 0; i < 32; ++i) {
    int idx = i * 256 + tid;
    int d2 = idx >> 6, c = idx & 63;
    wT[(c << 7) + (d2 ^ (c & 31))] = w_kv[idx];
  }
  const int gr0 = blockIdx.x << 1;
  if (tid < 128) {
    int r = tid >> 6, c = tid & 63;
    int gr = gr0 + r;
    float y = b_sr[c];
#pragma unroll
    for (int s = 0; s < 4; ++s) y += convP[((s << 11) + gr) * 64 + c];
    raw[r][c] = y;
  }
  __syncthreads();
  if (tid < 128) {
    int r = tid >> 6, c = tid & 63;
    float y = raw[r][c];
    float s1 = y, s2 = y * y;
#pragma unroll
    for (int off = 1; off < 64; off <<= 1) {
      s1 += __shfl_xor(s1, off);
      s2 += __shfl_xor(s2, off);
    }
    float mu = s1 * 0.015625f;
    float var = s2 * 0.015625f - mu * mu;
    float rs = rsqrtf(var + 1e-5f);
    rowz[r][c] = (y - mu) * rs * ln_g[c] + ln_b[c];
  }
  __syncthreads();
  {
    int r = tid >> 7, d = tid & 127;
    float acc = 0.f;
#pragma unroll
    for (int c = 0; c < 64; ++c) acc += rowz[r][c] * wT[(c << 7) + (d ^ (c & 31))];
    int gr = gr0 + r;
    int bb = gr >> 8, m = gr & 255;
    if (d < 64)
      Kw[((bb << 8) + m) * 64 + d] = f2bf(acc);
    else
      Vtw[((bb << 6) + (d - 64)) * 256 + m] = f2bf(acc);
  }
}

// ---------------- fused q-proj + attention + out-proj (v3) ----------------
// ONE 1024-thread block per CU (grid 256): 16 waves x 32 queries = 512 q/block.
// K/V staged once into swizzled LDS (coalesced uint4), then waves independent.
// LDS: K 32KB + V 32KB + 16x4KB Scr = 128KB -> 16 waves/CU (50% occupancy).
__global__ __launch_bounds__(1024, 1) void attn_k(
    const float* __restrict__ x, const short* __restrict__ Kw,
    const short* __restrict__ Vtw, const short* __restrict__ Wq,
    const short* __restrict__ Wp, const float* __restrict__ bproj,
    float* __restrict__ out) {
  __shared__ short Kl[256 * 64];    // rows 128B, slot ^= (row&7)   (R2-verified)
  __shared__ short Vl[64 * 256];    // rows 512B, scol=(s&24)|((s^d)&7) (R2-verified)
  __shared__ short Scr[16 * 2048];  // 4KB per wave

  const int tid = threadIdx.x;
  const int lane = tid & 63;
  const int wid = tid >> 6;
  const int b = blockIdx.x >> 5;          // 8 batches
  const int n0 = (blockIdx.x & 31) << 9;  // 512 tokens per block

  // ---- cooperative K/V staging (coalesced) ----
  {
    const uint4* Kg = (const uint4*)(Kw + ((size_t)b << 14));
    const uint4* Vg = (const uint4*)(Vtw + ((size_t)b << 14));
#pragma unroll
    for (int i = 0; i < 2; ++i) {
      int id = i * 1024 + tid;
      int row = id >> 3, s = id & 7;
      *(uint4*)(&Kl[(row << 6) + ((s ^ (row & 7)) << 3)]) = Kg[id];
    }
#pragma unroll
    for (int i = 0; i < 2; ++i) {
      int id = i * 1024 + tid;
      int d = id >> 5, s = id & 31;
      int scol = (s & 24) | ((s ^ d) & 7);
      *(uint4*)(&Vl[(d << 8) + (scol << 3)]) = Vg[id];
    }
  }
  __syncthreads();

  const int g = lane >> 4;
  const int kq = lane & 15;
  short* scr = &Scr[wid << 11];
  const int tok0 = n0 + wid * 32;
  const size_t xbase = ((size_t)b * NTOK + tok0) * 64;

  // ---- q projection ----
  f32x4 qa[2][4];
#pragma unroll
  for (int m = 0; m < 2; ++m)
#pragma unroll
    for (int nt = 0; nt < 4; ++nt) qa[m][nt] = (f32x4){0.f, 0.f, 0.f, 0.f};
  bf16x8 xa[2][2];
#pragma unroll
  for (int m = 0; m < 2; ++m)
#pragma unroll
    for (int kc = 0; kc < 2; ++kc) {
      const float* p = x + xbase + (size_t)(m * 16 + kq) * 64 + kc * 32 + g * 8;
      xa[m][kc] = cvt8(*(const f32x4*)p, *(const f32x4*)(p + 4));
    }
#pragma unroll
  for (int kc = 0; kc < 2; ++kc)
#pragma unroll
    for (int nt = 0; nt < 4; ++nt) {
      bf16x8 wb = *(const bf16x8*)(Wq + (nt * 16 + kq) * 64 + kc * 32 + g * 8);
#pragma unroll
      for (int m = 0; m < 2; ++m) qa[m][nt] = MFMA(xa[m][kc], wb, qa[m][nt]);
    }
  // stage q [32][64] bf16 (swizzled), read back as A-fragments
#pragma unroll
  for (int m = 0; m < 2; ++m)
#pragma unroll
    for (int nt = 0; nt < 4; ++nt)
#pragma unroll
      for (int r = 0; r < 4; ++r) {
        int row = m * 16 + g * 4 + r;
        int cb = ((nt * 16 + kq) << 1) ^ ((row & 7) << 4);
        scr[(row << 6) + (cb >> 1)] = f2bf(qa[m][nt][r]);
      }
  bf16x8 qf[2][2];
#pragma unroll
  for (int m = 0; m < 2; ++m)
#pragma unroll
    for (int kc = 0; kc < 2; ++kc) {
      int row = m * 16 + kq;
      int cb = (kc * 64 + g * 16) ^ ((row & 7) << 4);
      qf[m][kc] = *(const bf16x8*)(scr + (row << 6) + (cb >> 1));
    }

  float rsum[2][4];
#pragma unroll
  for (int m = 0; m < 2; ++m)
#pragma unroll
    for (int r = 0; r < 4; ++r) rsum[m][r] = 0.f;
  f32x4 pv[2][4];
#pragma unroll
  for (int m = 0; m < 2; ++m)
#pragma unroll
    for (int nd = 0; nd < 4; ++nd) pv[m][nd] = (f32x4){0.f, 0.f, 0.f, 0.f};

#pragma unroll
  for (int qr = 0; qr < 4; ++qr) {  // 64-key quarters
    f32x4 sa[2][4];
#pragma unroll
    for (int m = 0; m < 2; ++m)
#pragma unroll
      for (int ntk = 0; ntk < 4; ++ntk) sa[m][ntk] = (f32x4){0.f, 0.f, 0.f, 0.f};
    // S = q @ K^T  (K fragments from swizzled LDS)
#pragma unroll
    for (int ntk = 0; ntk < 4; ++ntk) {
      int key = qr * 64 + ntk * 16 + kq;
#pragma unroll
      for (int kc = 0; kc < 2; ++kc) {
        int slot = (kc * 4 + g) ^ (key & 7);
        bf16x8 kb = *(const bf16x8*)(&Kl[(key << 6) + (slot << 3)]);
#pragma unroll
        for (int m = 0; m < 2; ++m) sa[m][ntk] = MFMA(qf[m][kc], kb, sa[m][ntk]);
      }
    }
    // exp + rowsum + stage E [32][64] bf16 (swizzled)
#pragma unroll
    for (int m = 0; m < 2; ++m)
#pragma unroll
      for (int ntk = 0; ntk < 4; ++ntk)
#pragma unroll
        for (int r = 0; r < 4; ++r) {
          float e = __expf(sa[m][ntk][r]);
          rsum[m][r] += e;
          int row = m * 16 + g * 4 + r;
          int cb = ((ntk * 16 + kq) << 1) ^ ((row & 7) << 4);
          scr[(row << 6) + (cb >> 1)] = f2bf(e);
        }
    // PV for this quarter (V^T fragments from swizzled LDS)
#pragma unroll
    for (int kc2 = 0; kc2 < 2; ++kc2) {
      bf16x8 pa[2];
#pragma unroll
      for (int m = 0; m < 2; ++m) {
        int row = m * 16 + kq;
        int cb = (kc2 * 64 + g * 16) ^ ((row & 7) << 4);
        pa[m] = *(const bf16x8*)(scr + (row << 6) + (cb >> 1));
      }
#pragma unroll
      for (int nd = 0; nd < 4; ++nd) {
        int d = nd * 16 + kq;
        int s_lin = qr * 8 + kc2 * 4 + g;
        int scol = (s_lin & 24) | ((s_lin ^ d) & 7);
        bf16x8 vb = *(const bf16x8*)(&Vl[(d << 8) + (scol << 3)]);
#pragma unroll
        for (int m = 0; m < 2; ++m) pv[m][nd] = MFMA(pa[m], vb, pv[m][nd]);
      }
    }
  }
  // rowsum reduce across the 16 kq lanes, then normalize
#pragma unroll
  for (int m = 0; m < 2; ++m)
#pragma unroll
    for (int r = 0; r < 4; ++r) {
      float s = rsum[m][r];
      s += __shfl_xor(s, 1);
      s += __shfl_xor(s, 2);
      s += __shfl_xor(s, 4);
      s += __shfl_xor(s, 8);
      rsum[m][r] = 1.0f / s;
    }
#pragma unroll
  for (int m = 0; m < 2; ++m)
#pragma unroll
    for (int nd = 0; nd < 4; ++nd)
#pragma unroll
      for (int r = 0; r < 4; ++r) pv[m][nd][r] *= rsum[m][r];
  // stage out_attn [32][64] bf16, read back as A-fragments
#pragma unroll
  for (int m = 0; m < 2; ++m)
#pragma unroll
    for (int nd = 0; nd < 4; ++nd)
#pragma unroll
      for (int r = 0; r < 4; ++r) {
        int row = m * 16 + g * 4 + r;
        int cb = ((nd * 16 + kq) << 1) ^ ((row & 7) << 4);
        scr[(row << 6) + (cb >> 1)] = f2bf(pv[m][nd][r]);
      }
  bf16x8 of[2][2];
#pragma unroll
  for (int m = 0; m < 2; ++m)
#pragma unroll
    for (int kc = 0; kc < 2; ++kc) {
      int row = m * 16 + kq;
      int cb = (kc * 64 + g * 16) ^ ((row & 7) << 4);
      of[m][kc] = *(const bf16x8*)(scr + (row << 6) + (cb >> 1));
    }
  // out projection
  f32x4 pj[2][4];
#pragma unroll
  for (int m = 0; m < 2; ++m)
#pragma unroll
    for (int nt = 0; nt < 4; ++nt) pj[m][nt] = (f32x4){0.f, 0.f, 0.f, 0.f};
#pragma unroll
  for (int kc = 0; kc < 2; ++kc)
#pragma unroll
    for (int nt = 0; nt < 4; ++nt) {
      bf16x8 wb = *(const bf16x8*)(Wp + (nt * 16 + kq) * 64 + kc * 32 + g * 8);
#pragma unroll
      for (int m = 0; m < 2; ++m) pj[m][nt] = MFMA(of[m][kc], wb, pj[m][nt]);
    }
  // epilogue: two 16-row half-passes through 4KB scratch (f32) + bias + stores
  float* sf = (float*)scr;
  const f32x4* bp4 = (const f32x4*)bproj;
#pragma unroll
  for (int p = 0; p < 2; ++p) {
#pragma unroll
    for (int nt = 0; nt < 4; ++nt)
#pragma unroll
      for (int r = 0; r < 4; ++r) {
        int row = g * 4 + r;  // tile-local
        int j = nt * 16 + kq;
        int cb = (j << 2) ^ ((row & 7) << 4);
        sf[(row << 6) + (cb >> 2)] = pj[p][nt][r];
      }
#pragma unroll
    for (int i = 0; i < 4; ++i) {
      int idx = i * 64 + lane;
      int trow = idx >> 4, seg = idx & 15;
      int cb = (seg << 4) ^ ((trow & 7) << 4);
      f32x4 v = *(const f32x4*)(sf + (trow << 6) + (cb >> 2));
      v += bp4[seg];
      *(f32x4*)(out + xbase + (size_t)(p * 16 + trow) * 64 + seg * 4) = v;
    }
  }
}

extern "C" void kernel_launch(void* const* d_in, const int* in_sizes, int n_in,
                              void* d_out, int out_size, void* d_ws, size_t ws_size,
                              hipStream_t stream) {
  const float* x = (const float*)d_in[0];
  const float* w_q = (const float*)d_in[3];
  const float* w_kv = (const float*)d_in[4];
  const float* w_sr = (const float*)d_in[5];
  const float* b_sr = (const float*)d_in[6];
  const float* ln_g = (const float*)d_in[7];
  const float* ln_b = (const float*)d_in[8];
  const float* w_proj = (const float*)d_in[9];
  const float* b_proj = (const float*)d_in[10];
  float* out = (float*)d_out;

  // workspace layout: identical to the R2/R6-passing runs (3,162,112 B total)
  char* ws = (char*)d_ws;
  short* W2T = (short*)(ws);              // 524288 B
  short* Wq = (short*)(ws + 524288);      // 8192 B
  short* Wp = (short*)(ws + 532480);      // 8192 B
  float* convP = (float*)(ws + 540672);   // 4*2048*64*4 = 2097152 B
  short* Kw = (short*)(ws + 2637824);     // 262144 B
  short* Vtw = (short*)(ws + 2899968);    // 262144 B (end 3162112)

  hipLaunchKernelGGL(prep_k, dim3(1056), dim3(256), 0, stream, w_sr, w_q, w_proj,
                     W2T, Wq, Wp);
  hipLaunchKernelGGL(conv_k, dim3(512), dim3(256), 0, stream, x, W2T, convP);
  hipLaunchKernelGGL(kv_k, dim3(1024), dim3(256), 0, stream, convP, b_sr, ln_g,
                     ln_b, w_kv, Kw, Vtw);
  hipLaunchKernelGGL(attn_k, dim3(256), dim3(1024), 0, stream, x, Kw, Vtw, Wq, Wp,
                     b_proj, out);
}